// Round 2
// baseline (451.065 us; speedup 1.0000x reference)
//
#include <hip/hip_runtime.h>

#define H 2048
#define W 2048
#define NIMG 4
#define HWPX (H*W)               // 4194304 = 2^22
#define K_RANK 2097151u          // (n-1)//2

__device__ __forceinline__ unsigned fmap(float f) {
    unsigned u = __float_as_uint(f);
    return (u & 0x80000000u) ? ~u : (u | 0x80000000u);
}

// ---------------- P1: fused sobel + f64 products + direct 7x7 f64 gaussian -> R(f32)
// tile 64 wide x 32 tall, 256 threads, each thread computes 2 cols x 4 rows
__global__ __launch_bounds__(256) void k_harris_R(const float* __restrict__ x,
                                                  const float* __restrict__ gkq,
                                                  float* __restrict__ R)
{
    __shared__ float xs[40*72];                       // rows y0-4..y0+35, cols x0-4..x0+67
    __align__(16) __shared__ double prods[3*38*72];   // 3ch, rows y0-3.., cols x0-3.. (70 valid, stride 72)
    __shared__ double kw[49];

    const int tid = threadIdx.x;
    const int img = blockIdx.z;
    const int x0 = blockIdx.x * 64, y0 = blockIdx.y * 32;
    const float* __restrict__ X = x + (size_t)img * HWPX;

    if (tid < 49) kw[tid] = (double)gkq[tid];

    for (int i = tid; i < 2880; i += 256) {
        int r = i / 72, c = i - r * 72;
        int gy = y0 - 4 + r, gx = x0 - 4 + c;
        float v = 0.f;
        if ((unsigned)gy < H && (unsigned)gx < W) v = X[(size_t)gy * W + gx];
        xs[i] = v;
    }
    __syncthreads();

    // sobel + products (f64) on 38 rows x 70 cols; zero outside image (gaussian zero-pad)
    for (int g = tid; g < 38 * 18; g += 256) {
        int r = g / 18, c0 = (g - r * 18) * 4;
        #pragma unroll
        for (int cc = 0; cc < 4; cc++) {
            int pc = c0 + cc;
            if (pc >= 70) break;
            int gy = y0 - 3 + r, gx = x0 - 3 + pc;
            double pxx = 0.0, pyy = 0.0, pxy = 0.0;
            if ((unsigned)gy < H && (unsigned)gx < W) {
                const float* p0 = &xs[r * 72 + pc];
                double x00 = p0[0],   x01 = p0[1],   x02 = p0[2];
                double x10 = p0[72],                  x12 = p0[74];
                double x20 = p0[144], x21 = p0[145], x22 = p0[146];
                double ix = (x02 - x00) + 2.0 * (x12 - x10) + (x22 - x20);
                double iy = (x20 - x00) + 2.0 * (x21 - x01) + (x22 - x02);
                pxx = ix * ix; pyy = iy * iy; pxy = ix * iy;
            }
            prods[(0*38 + r)*72 + pc] = pxx;
            prods[(1*38 + r)*72 + pc] = pyy;
            prods[(2*38 + r)*72 + pc] = pxy;
        }
    }
    __syncthreads();

    const int tc = (tid & 31) * 2;      // 0..62 (output cols tc, tc+1)
    const int tr = (tid >> 5) * 4;      // 0..28 (output rows tr..tr+3)

    double acc[3][4][2];
    #pragma unroll
    for (int a = 0; a < 3; a++)
        #pragma unroll
        for (int b = 0; b < 4; b++) { acc[a][b][0] = 0.0; acc[a][b][1] = 0.0; }

    double wA[7], wB[7], wC[7], wD[7];
    #pragma unroll
    for (int k = 0; k < 7; k++) { wA[k] = 0.0; wB[k] = 0.0; wC[k] = 0.0; wD[k] = 0.0; }

    #pragma unroll
    for (int i = 0; i < 10; i++) {
        #pragma unroll
        for (int k = 0; k < 7; k++) { wD[k] = wC[k]; wC[k] = wB[k]; wB[k] = wA[k]; }
        if (i <= 6) {
            #pragma unroll
            for (int k = 0; k < 7; k++) wA[k] = kw[i * 7 + k];
        }
        const int pr = tr + i;
        #pragma unroll
        for (int ch = 0; ch < 3; ch++) {
            double pv[8];
            const double2* prow = (const double2*)&prods[(ch*38 + pr)*72 + tc];
            #pragma unroll
            for (int j2 = 0; j2 < 4; j2++) { double2 t = prow[j2]; pv[2*j2] = t.x; pv[2*j2+1] = t.y; }

            if (i <= 6) {                       // rr = 0, weight row i
                #pragma unroll
                for (int cc = 0; cc < 2; cc++) {
                    double s = acc[ch][0][cc];
                    #pragma unroll
                    for (int j = 0; j < 7; j++) s = fma(wA[j], pv[cc + j], s);
                    acc[ch][0][cc] = s;
                }
            }
            if (i >= 1 && i <= 7) {             // rr = 1, weight row i-1
                #pragma unroll
                for (int cc = 0; cc < 2; cc++) {
                    double s = acc[ch][1][cc];
                    #pragma unroll
                    for (int j = 0; j < 7; j++) s = fma(wB[j], pv[cc + j], s);
                    acc[ch][1][cc] = s;
                }
            }
            if (i >= 2 && i <= 8) {             // rr = 2, weight row i-2
                #pragma unroll
                for (int cc = 0; cc < 2; cc++) {
                    double s = acc[ch][2][cc];
                    #pragma unroll
                    for (int j = 0; j < 7; j++) s = fma(wC[j], pv[cc + j], s);
                    acc[ch][2][cc] = s;
                }
            }
            if (i >= 3) {                       // rr = 3, weight row i-3
                #pragma unroll
                for (int cc = 0; cc < 2; cc++) {
                    double s = acc[ch][3][cc];
                    #pragma unroll
                    for (int j = 0; j < 7; j++) s = fma(wD[j], pv[cc + j], s);
                    acc[ch][3][cc] = s;
                }
            }
        }
    }

    float* __restrict__ Ri = R + (size_t)img * HWPX;
    #pragma unroll
    for (int rr = 0; rr < 4; rr++) {
        float2 o;
        #pragma unroll
        for (int cc = 0; cc < 2; cc++) {
            double sxx = acc[0][rr][cc], syy = acc[1][rr][cc], sxy = acc[2][rr][cc];
            double t2 = sxx + syy;
            double Rv = sxx * syy - sxy * sxy - 0.05 * t2 * t2;
            ((float*)&o)[cc] = (float)Rv;
        }
        *(float2*)&Ri[(size_t)(y0 + tr + rr) * W + (x0 + tc)] = o;
    }
}

// ---------------- P1b: top-12-bit histogram of R
__global__ __launch_bounds__(256) void k_hist1(const float* __restrict__ R,
                                               unsigned* __restrict__ hist1)
{
    __shared__ unsigned h[4096];
    const int tid = threadIdx.x;
    const int img = blockIdx.y;
    for (int i = tid; i < 4096; i += 256) h[i] = 0;
    __syncthreads();
    const float4* __restrict__ R4 = (const float4*)(R + ((size_t)img << 22)) + (size_t)blockIdx.x * 4096;
    #pragma unroll
    for (int j = 0; j < 16; j++) {
        float4 v = R4[tid + j * 256];
        atomicAdd(&h[fmap(v.x) >> 20], 1u);
        atomicAdd(&h[fmap(v.y) >> 20], 1u);
        atomicAdd(&h[fmap(v.z) >> 20], 1u);
        atomicAdd(&h[fmap(v.w) >> 20], 1u);
    }
    __syncthreads();
    unsigned* gh = hist1 + img * 4096;
    for (int i = tid; i < 4096; i += 256) {
        unsigned v = h[i];
        if (v) atomicAdd(&gh[i], v);
    }
}

// ---------------- P2: scan hist1 -> coarse bin + count below
__global__ __launch_bounds__(256) void k_scan1(const unsigned* __restrict__ hist1,
                                               int* __restrict__ metaBin,
                                               int* __restrict__ metaBase)
{
    int img = blockIdx.x, tid = threadIdx.x;
    __shared__ unsigned s[256];
    const unsigned* h = hist1 + img * 4096;
    unsigned loc[16], sum = 0;
    #pragma unroll
    for (int j = 0; j < 16; j++) { loc[j] = h[tid * 16 + j]; sum += loc[j]; }
    s[tid] = sum; __syncthreads();
    for (int off = 1; off < 256; off <<= 1) {
        unsigned v = (tid >= off) ? s[tid - off] : 0; __syncthreads();
        s[tid] += v; __syncthreads();
    }
    unsigned incl = s[tid], excl = incl - sum;
    if (K_RANK >= excl && K_RANK < incl) {
        unsigned run = excl;
        #pragma unroll
        for (int j = 0; j < 16; j++) {
            if (K_RANK < run + loc[j]) { metaBin[img] = tid * 16 + j; metaBase[img] = (int)run; break; }
            run += loc[j];
        }
    }
}

// ---------------- P3: refine histogram (low 20 bits) for values in the selected bin
__global__ __launch_bounds__(256) void k_hist2(const float* __restrict__ R,
                                               const int* __restrict__ metaBin,
                                               unsigned* __restrict__ hist2)
{
    int img = blockIdx.x >> 10;                 // 1024 blocks per image
    unsigned b1 = (unsigned)metaBin[img];
    unsigned* h2 = hist2 + ((size_t)img << 20);
    const float4* __restrict__ R4 = (const float4*)R + (size_t)blockIdx.x * 1024;
    #pragma unroll
    for (int j = 0; j < 4; j++) {
        float4 v = R4[threadIdx.x + j * 256];
        unsigned ux = fmap(v.x), uy = fmap(v.y), uz = fmap(v.z), uw = fmap(v.w);
        if ((ux >> 20) == b1) atomicAdd(&h2[ux & 0xFFFFFu], 1u);
        if ((uy >> 20) == b1) atomicAdd(&h2[uy & 0xFFFFFu], 1u);
        if ((uz >> 20) == b1) atomicAdd(&h2[uz & 0xFFFFFu], 1u);
        if ((uw >> 20) == b1) atomicAdd(&h2[uw & 0xFFFFFu], 1u);
    }
}

// ---------------- P4a: chunk sums of hist2 (256 chunks of 4096 bins per image)
__global__ __launch_bounds__(256) void k_chunks(const unsigned* __restrict__ hist2,
                                                unsigned* __restrict__ chunkSum)
{
    int img = blockIdx.y, cb = blockIdx.x, tid = threadIdx.x;
    const unsigned* h = hist2 + ((size_t)img << 20) + cb * 4096;
    unsigned s = 0;
    #pragma unroll
    for (int j = 0; j < 16; j++) s += h[tid + j * 256];
    __shared__ unsigned red[256];
    red[tid] = s; __syncthreads();
    for (int off = 128; off > 0; off >>= 1) {
        if (tid < off) red[tid] += red[tid + off];
        __syncthreads();
    }
    if (tid == 0) chunkSum[img * 256 + cb] = red[0];
}

// ---------------- P4b: locate chunk, then exact bin -> median value
__global__ __launch_bounds__(256) void k_scan2(const unsigned* __restrict__ hist2,
                                               const unsigned* __restrict__ chunkSum,
                                               const int* __restrict__ metaBin,
                                               const int* __restrict__ metaBase,
                                               float* __restrict__ med)
{
    int img = blockIdx.x, tid = threadIdx.x;
    __shared__ unsigned s[256];
    __shared__ int sel[2];
    unsigned target = K_RANK - (unsigned)metaBase[img];
    unsigned v = chunkSum[img * 256 + tid];
    s[tid] = v; __syncthreads();
    for (int off = 1; off < 256; off <<= 1) {
        unsigned t2 = (tid >= off) ? s[tid - off] : 0; __syncthreads();
        s[tid] += t2; __syncthreads();
    }
    unsigned incl = s[tid], excl = incl - v;
    if (target >= excl && target < incl) { sel[0] = tid; sel[1] = (int)excl; }
    __syncthreads();
    int cb = sel[0];
    unsigned cexcl = (unsigned)sel[1];

    const unsigned* h = hist2 + ((size_t)img << 20) + cb * 4096;
    unsigned loc[16], sum = 0;
    #pragma unroll
    for (int j = 0; j < 16; j++) { loc[j] = h[tid * 16 + j]; sum += loc[j]; }
    __syncthreads();
    s[tid] = sum; __syncthreads();
    for (int off = 1; off < 256; off <<= 1) {
        unsigned t2 = (tid >= off) ? s[tid - off] : 0; __syncthreads();
        s[tid] += t2; __syncthreads();
    }
    incl = s[tid] + cexcl; excl = s[tid] - sum + cexcl;
    if (target >= excl && target < incl) {
        unsigned run = excl;
        #pragma unroll
        for (int j = 0; j < 16; j++) {
            if (target < run + loc[j]) {
                unsigned c = (unsigned)cb * 4096u + (unsigned)tid * 16u + (unsigned)j;
                unsigned mu = (((unsigned)metaBin[img]) << 20) | c;
                unsigned fb = (mu & 0x80000000u) ? (mu & 0x7FFFFFFFu) : ~mu;
                med[img] = __uint_as_float(fb);
                break;
            }
            run += loc[j];
        }
    }
}

// ---------------- P5: threshold + separable 7x7 max-pool + equality write
__global__ __launch_bounds__(256) void k_out(const float* __restrict__ R,
                                             const float* __restrict__ med,
                                             float* __restrict__ out)
{
    __shared__ float rt[38][39];
    __shared__ float hm[38][33];
    const int tid = threadIdx.x;
    const int img = blockIdx.z;
    const int x0 = blockIdx.x * 32, y0 = blockIdx.y * 32;
    const float m = med[img];
    const float* __restrict__ Ri = R + ((size_t)img << 22);

    for (int i = tid; i < 1444; i += 256) {
        int r = i / 38, c = i - r * 38;
        int gy = y0 - 3 + r, gx = x0 - 3 + c;
        float v = -INFINITY;                      // reduce_window pad = -inf
        if ((unsigned)gy < H && (unsigned)gx < W) {
            float rv = Ri[(size_t)gy * W + gx];
            v = (rv >= m) ? rv : 0.0f;
        }
        rt[r][c] = v;
    }
    __syncthreads();

    for (int i = tid; i < 1216; i += 256) {
        int r = i >> 5, c = i & 31;
        float mx = rt[r][c];
        #pragma unroll
        for (int j = 1; j < 7; j++) mx = fmaxf(mx, rt[r][c + j]);
        hm[r][c] = mx;
    }
    __syncthreads();

    const int txc = tid & 31, ty0 = tid >> 5;
    float* __restrict__ Oi = out + ((size_t)img << 22);
    #pragma unroll
    for (int q = 0; q < 4; q++) {
        int ty = ty0 + q * 8;
        float mx = hm[ty][txc];
        #pragma unroll
        for (int j = 1; j < 7; j++) mx = fmaxf(mx, hm[ty + j][txc]);
        float c = rt[ty + 3][txc + 3];
        Oi[(size_t)(y0 + ty) * W + (x0 + txc)] = (c == mx) ? c : 0.0f;
    }
}

extern "C" void kernel_launch(void* const* d_in, const int* in_sizes, int n_in,
                              void* d_out, int out_size, void* d_ws, size_t ws_size,
                              hipStream_t stream)
{
    const float* x  = (const float*)d_in[0];
    const float* gk = (const float*)d_in[2];        // 7x7 gaussian (49 floats)
    float* out = (float*)d_out;

    char* ws = (char*)d_ws;
    float*    R        = (float*)ws;                               // 64 MB
    unsigned* hist1    = (unsigned*)(ws + (size_t)HWPX * NIMG * 4);// 64 KB
    unsigned* chunkSum = hist1 + NIMG * 4096;                      // 4 KB
    int*      metaBin  = (int*)(chunkSum + NIMG * 256);
    int*      metaBase = metaBin + NIMG;
    float*    med      = (float*)(metaBase + NIMG);
    unsigned* hist2    = (unsigned*)d_out;                         // 16 MB scratch until P5

    hipMemsetAsync(hist1, 0, (size_t)NIMG * 4096 * 4, stream);
    hipMemsetAsync(hist2, 0, (size_t)NIMG * (1u << 20) * 4, stream);

    k_harris_R<<<dim3(32, 64, NIMG), 256, 0, stream>>>(x, gk, R);
    k_hist1  <<<dim3(256, NIMG), 256, 0, stream>>>(R, hist1);
    k_scan1  <<<NIMG, 256, 0, stream>>>(hist1, metaBin, metaBase);
    k_hist2  <<<4096, 256, 0, stream>>>(R, metaBin, hist2);
    k_chunks <<<dim3(256, NIMG), 256, 0, stream>>>(hist2, chunkSum);
    k_scan2  <<<NIMG, 256, 0, stream>>>(hist2, chunkSum, metaBin, metaBase, med);
    k_out    <<<dim3(64, 64, NIMG), 256, 0, stream>>>(R, med, out);
}

// Round 3
// 274.190 us; speedup vs baseline: 1.6451x; 1.6451x over previous
//
#include <hip/hip_runtime.h>

#define H 2048
#define W 2048
#define NIMG 4
#define HWPX (H*W)               // 4194304 = 2^22
#define K_RANK 2097151u          // (n-1)//2

__device__ __forceinline__ unsigned fmap(float f) {
    unsigned u = __float_as_uint(f);
    return (u & 0x80000000u) ? ~u : (u | 0x80000000u);
}

// ---------------- P0: convert f32 gaussian taps to f64 in ws (uniform s_load'able)
__global__ void k_prep(const float* __restrict__ gk, double* __restrict__ kwd) {
    int t = threadIdx.x;
    if (t < 49) kwd[t] = (double)gk[t];
}

// ---------------- P1: fused sobel + on-the-fly f64 products + 7x7 f64 conv -> R(f32) + hist
// tile 64w x 32h, 512 threads, each thread 2 cols x 2 rows
__global__ __launch_bounds__(512, 4) void k_harris_R(const float* __restrict__ x,
                                                     const double* __restrict__ kwd,
                                                     float* __restrict__ R,
                                                     unsigned* __restrict__ hist1)
{
    __shared__ float xs[4096];                 // [40][72] f32 (2880 used); union: hist[4096] u32
    __align__(16) __shared__ double ixiy[2*38*72];  // ix plane [38][72], iy plane [38][72]
    unsigned* hist = (unsigned*)xs;

    const int tid = threadIdx.x;
    const int img = blockIdx.z;
    const int x0 = blockIdx.x * 64, y0 = blockIdx.y * 32;
    const float* __restrict__ X = x + (size_t)img * HWPX;

    // stage x tile with halo 4 (zero-padded), rows y0-4..y0+35, cols x0-4..x0+67
    for (int i = tid; i < 2880; i += 512) {
        int r = i / 72, c = i - r * 72;
        int gy = y0 - 4 + r, gx = x0 - 4 + c;
        float v = 0.f;
        if ((unsigned)gy < H && (unsigned)gx < W) v = X[(size_t)gy * W + gx];
        xs[i] = v;
    }
    __syncthreads();

    // sobel in f64: ix/iy for product rows 0..37 (image rows y0-3..), cols 0..69 (x0-3..)
    for (int i = tid; i < 2736; i += 512) {    // 38*72
        int r = i / 72, c = i - r * 72;
        double ix = 0.0, iy = 0.0;
        int gy = y0 - 3 + r, gx = x0 - 3 + c;
        if (c < 70 && (unsigned)gy < H && (unsigned)gx < W) {
            const float* p0 = &xs[r * 72 + c];
            double x00 = p0[0],   x01 = p0[1],   x02 = p0[2];
            double x10 = p0[72],                  x12 = p0[74];
            double x20 = p0[144], x21 = p0[145], x22 = p0[146];
            ix = (x02 - x00) + 2.0 * (x12 - x10) + (x22 - x20);
            iy = (x20 - x00) + 2.0 * (x21 - x01) + (x22 - x02);
        }
        ixiy[i] = ix;
        ixiy[2736 + i] = iy;
    }
    __syncthreads();

    // xs is dead -> reuse as LDS histogram
    for (int i = tid; i < 4096; i += 512) hist[i] = 0;
    __syncthreads();

    const int tc = (tid & 31) * 2;       // cols tc, tc+1 (0..62)
    const int tr = (tid >> 5) * 2;       // rows tr, tr+1 (0..30)

    double axx[2][2], ayy[2][2], axy[2][2];
    #pragma unroll
    for (int rr = 0; rr < 2; rr++)
        #pragma unroll
        for (int cc = 0; cc < 2; cc++) { axx[rr][cc] = 0.0; ayy[rr][cc] = 0.0; axy[rr][cc] = 0.0; }

    #pragma unroll
    for (int ii = 0; ii < 8; ii++) {
        const int prow = tr + ii;
        double vx[8], vy[8];
        const double2* rx = (const double2*)&ixiy[prow * 72 + tc];
        const double2* ry = (const double2*)&ixiy[2736 + prow * 72 + tc];
        #pragma unroll
        for (int q = 0; q < 4; q++) {
            double2 t = rx[q]; vx[2*q] = t.x; vx[2*q+1] = t.y;
            double2 u = ry[q]; vy[2*q] = u.x; vy[2*q+1] = u.y;
        }
        // rolling products: p = j for col0, p = j+1 for col1
        double xx0 = vx[0]*vx[0], yy0 = vy[0]*vy[0], xy0 = vx[0]*vy[0];
        #pragma unroll
        for (int j = 0; j < 7; j++) {
            double xx1 = vx[j+1]*vx[j+1], yy1 = vy[j+1]*vy[j+1], xy1 = vx[j+1]*vy[j+1];
            #pragma unroll
            for (int rr = 0; rr < 2; rr++) {
                const int wrow = ii - rr;
                if (wrow >= 0 && wrow <= 6) {
                    double w = kwd[wrow * 7 + j];
                    axx[rr][0] = fma(w, xx0, axx[rr][0]); axx[rr][1] = fma(w, xx1, axx[rr][1]);
                    ayy[rr][0] = fma(w, yy0, ayy[rr][0]); ayy[rr][1] = fma(w, yy1, ayy[rr][1]);
                    axy[rr][0] = fma(w, xy0, axy[rr][0]); axy[rr][1] = fma(w, xy1, axy[rr][1]);
                }
            }
            xx0 = xx1; yy0 = yy1; xy0 = xy1;
        }
    }

    float* __restrict__ Ri = R + (size_t)img * HWPX;
    #pragma unroll
    for (int rr = 0; rr < 2; rr++) {
        float2 o;
        #pragma unroll
        for (int cc = 0; cc < 2; cc++) {
            double sxx = axx[rr][cc], syy = ayy[rr][cc], sxy = axy[rr][cc];
            double t2 = sxx + syy;
            double Rv = sxx * syy - sxy * sxy - 0.05 * t2 * t2;
            ((float*)&o)[cc] = (float)Rv;
        }
        *(float2*)&Ri[(size_t)(y0 + tr + rr) * W + (x0 + tc)] = o;
        atomicAdd(&hist[fmap(o.x) >> 20], 1u);
        atomicAdd(&hist[fmap(o.y) >> 20], 1u);
    }
    __syncthreads();

    unsigned* gh = hist1 + img * 4096;
    for (int i = tid; i < 4096; i += 512) {
        unsigned v = hist[i];
        if (v) atomicAdd(&gh[i], v);
    }
}

// ---------------- P2: scan hist1 -> coarse bin + count below
__global__ __launch_bounds__(256) void k_scan1(const unsigned* __restrict__ hist1,
                                               int* __restrict__ metaBin,
                                               int* __restrict__ metaBase)
{
    int img = blockIdx.x, tid = threadIdx.x;
    __shared__ unsigned s[256];
    const unsigned* h = hist1 + img * 4096;
    unsigned loc[16], sum = 0;
    #pragma unroll
    for (int j = 0; j < 16; j++) { loc[j] = h[tid * 16 + j]; sum += loc[j]; }
    s[tid] = sum; __syncthreads();
    for (int off = 1; off < 256; off <<= 1) {
        unsigned v = (tid >= off) ? s[tid - off] : 0; __syncthreads();
        s[tid] += v; __syncthreads();
    }
    unsigned incl = s[tid], excl = incl - sum;
    if (K_RANK >= excl && K_RANK < incl) {
        unsigned run = excl;
        #pragma unroll
        for (int j = 0; j < 16; j++) {
            if (K_RANK < run + loc[j]) { metaBin[img] = tid * 16 + j; metaBase[img] = (int)run; break; }
            run += loc[j];
        }
    }
}

// ---------------- P3: refine histogram (low 20 bits) for values in the selected bin
__global__ __launch_bounds__(256) void k_hist2(const float* __restrict__ R,
                                               const int* __restrict__ metaBin,
                                               unsigned* __restrict__ hist2)
{
    int img = blockIdx.x >> 10;                 // 1024 blocks per image
    unsigned b1 = (unsigned)metaBin[img];
    unsigned* h2 = hist2 + ((size_t)img << 20);
    const float4* __restrict__ R4 = (const float4*)R + (size_t)blockIdx.x * 1024;
    #pragma unroll
    for (int j = 0; j < 4; j++) {
        float4 v = R4[threadIdx.x + j * 256];
        unsigned ux = fmap(v.x), uy = fmap(v.y), uz = fmap(v.z), uw = fmap(v.w);
        if ((ux >> 20) == b1) atomicAdd(&h2[ux & 0xFFFFFu], 1u);
        if ((uy >> 20) == b1) atomicAdd(&h2[uy & 0xFFFFFu], 1u);
        if ((uz >> 20) == b1) atomicAdd(&h2[uz & 0xFFFFFu], 1u);
        if ((uw >> 20) == b1) atomicAdd(&h2[uw & 0xFFFFFu], 1u);
    }
}

// ---------------- P4a: chunk sums of hist2 (256 chunks of 4096 bins per image)
__global__ __launch_bounds__(256) void k_chunks(const unsigned* __restrict__ hist2,
                                                unsigned* __restrict__ chunkSum)
{
    int img = blockIdx.y, cb = blockIdx.x, tid = threadIdx.x;
    const unsigned* h = hist2 + ((size_t)img << 20) + cb * 4096;
    unsigned s = 0;
    #pragma unroll
    for (int j = 0; j < 16; j++) s += h[tid + j * 256];
    __shared__ unsigned red[256];
    red[tid] = s; __syncthreads();
    for (int off = 128; off > 0; off >>= 1) {
        if (tid < off) red[tid] += red[tid + off];
        __syncthreads();
    }
    if (tid == 0) chunkSum[img * 256 + cb] = red[0];
}

// ---------------- P4b: locate chunk, then exact bin -> median value
__global__ __launch_bounds__(256) void k_scan2(const unsigned* __restrict__ hist2,
                                               const unsigned* __restrict__ chunkSum,
                                               const int* __restrict__ metaBin,
                                               const int* __restrict__ metaBase,
                                               float* __restrict__ med)
{
    int img = blockIdx.x, tid = threadIdx.x;
    __shared__ unsigned s[256];
    __shared__ int sel[2];
    unsigned target = K_RANK - (unsigned)metaBase[img];
    unsigned v = chunkSum[img * 256 + tid];
    s[tid] = v; __syncthreads();
    for (int off = 1; off < 256; off <<= 1) {
        unsigned t2 = (tid >= off) ? s[tid - off] : 0; __syncthreads();
        s[tid] += t2; __syncthreads();
    }
    unsigned incl = s[tid], excl = incl - v;
    if (target >= excl && target < incl) { sel[0] = tid; sel[1] = (int)excl; }
    __syncthreads();
    int cb = sel[0];
    unsigned cexcl = (unsigned)sel[1];

    const unsigned* h = hist2 + ((size_t)img << 20) + cb * 4096;
    unsigned loc[16], sum = 0;
    #pragma unroll
    for (int j = 0; j < 16; j++) { loc[j] = h[tid * 16 + j]; sum += loc[j]; }
    __syncthreads();
    s[tid] = sum; __syncthreads();
    for (int off = 1; off < 256; off <<= 1) {
        unsigned t2 = (tid >= off) ? s[tid - off] : 0; __syncthreads();
        s[tid] += t2; __syncthreads();
    }
    incl = s[tid] + cexcl; excl = s[tid] - sum + cexcl;
    if (target >= excl && target < incl) {
        unsigned run = excl;
        #pragma unroll
        for (int j = 0; j < 16; j++) {
            if (target < run + loc[j]) {
                unsigned c = (unsigned)cb * 4096u + (unsigned)tid * 16u + (unsigned)j;
                unsigned mu = (((unsigned)metaBin[img]) << 20) | c;
                unsigned fb = (mu & 0x80000000u) ? (mu & 0x7FFFFFFFu) : ~mu;
                med[img] = __uint_as_float(fb);
                break;
            }
            run += loc[j];
        }
    }
}

// ---------------- P5: threshold + separable 7x7 max-pool + equality write
__global__ __launch_bounds__(256) void k_out(const float* __restrict__ R,
                                             const float* __restrict__ med,
                                             float* __restrict__ out)
{
    __shared__ float rt[38][39];
    __shared__ float hm[38][33];
    const int tid = threadIdx.x;
    const int img = blockIdx.z;
    const int x0 = blockIdx.x * 32, y0 = blockIdx.y * 32;
    const float m = med[img];
    const float* __restrict__ Ri = R + ((size_t)img << 22);

    for (int i = tid; i < 1444; i += 256) {
        int r = i / 38, c = i - r * 38;
        int gy = y0 - 3 + r, gx = x0 - 3 + c;
        float v = -INFINITY;                      // reduce_window pad = -inf
        if ((unsigned)gy < H && (unsigned)gx < W) {
            float rv = Ri[(size_t)gy * W + gx];
            v = (rv >= m) ? rv : 0.0f;
        }
        rt[r][c] = v;
    }
    __syncthreads();

    for (int i = tid; i < 1216; i += 256) {
        int r = i >> 5, c = i & 31;
        float mx = rt[r][c];
        #pragma unroll
        for (int j = 1; j < 7; j++) mx = fmaxf(mx, rt[r][c + j]);
        hm[r][c] = mx;
    }
    __syncthreads();

    const int txc = tid & 31, ty0 = tid >> 5;
    float* __restrict__ Oi = out + ((size_t)img << 22);
    #pragma unroll
    for (int q = 0; q < 4; q++) {
        int ty = ty0 + q * 8;
        float mx = hm[ty][txc];
        #pragma unroll
        for (int j = 1; j < 7; j++) mx = fmaxf(mx, hm[ty + j][txc]);
        float c = rt[ty + 3][txc + 3];
        Oi[(size_t)(y0 + ty) * W + (x0 + txc)] = (c == mx) ? c : 0.0f;
    }
}

extern "C" void kernel_launch(void* const* d_in, const int* in_sizes, int n_in,
                              void* d_out, int out_size, void* d_ws, size_t ws_size,
                              hipStream_t stream)
{
    const float* x  = (const float*)d_in[0];
    const float* gk = (const float*)d_in[2];        // 7x7 gaussian (49 floats)
    float* out = (float*)d_out;

    char* ws = (char*)d_ws;
    float*    R        = (float*)ws;                               // 64 MB
    unsigned* hist1    = (unsigned*)(ws + (size_t)HWPX * NIMG * 4);// 64 KB
    unsigned* chunkSum = hist1 + NIMG * 4096;                      // 4 KB
    int*      metaBin  = (int*)(chunkSum + NIMG * 256);
    int*      metaBase = metaBin + NIMG;
    float*    med      = (float*)(metaBase + NIMG);
    double*   kwd      = (double*)(med + NIMG + 1);                // 8B-aligned (offset 65584)
    unsigned* hist2    = (unsigned*)d_out;                         // 16 MB scratch until P5

    hipMemsetAsync(hist1, 0, (size_t)NIMG * 4096 * 4, stream);
    hipMemsetAsync(hist2, 0, (size_t)NIMG * (1u << 20) * 4, stream);

    k_prep    <<<1, 64, 0, stream>>>(gk, kwd);
    k_harris_R<<<dim3(32, 64, NIMG), 512, 0, stream>>>(x, kwd, R, hist1);
    k_scan1  <<<NIMG, 256, 0, stream>>>(hist1, metaBin, metaBase);
    k_hist2  <<<4096, 256, 0, stream>>>(R, metaBin, hist2);
    k_chunks <<<dim3(256, NIMG), 256, 0, stream>>>(hist2, chunkSum);
    k_scan2  <<<NIMG, 256, 0, stream>>>(hist2, chunkSum, metaBin, metaBase, med);
    k_out    <<<dim3(64, 64, NIMG), 256, 0, stream>>>(R, med, out);
}